// Round 6
// baseline (199.827 us; speedup 1.0000x reference)
//
#include <hip/hip_runtime.h>

// Fused ISTFT as one MFMA GEMM, j-major K layout:
//   out[(b,g)][n] = ( sum_{k''} A[m'][k''] * Bfold[k''][n] ) / wsum[n]
// k'' = j*1088 + c; c<544: re[kk=c], else im[kk=c-544] (valid kk<513, zero-pad).
// A-image (LINEAR bf16, rows f = b*2048 + t, 1088 elems = 2176 B):
//   row f = [ re[f][0..512], 0 pad .. 543, im[f][0..512], 0 pad .. 1087 ]
// Bfold[j*1088+c][n] = f(kk)*Wr[kk][n+256j] / -f(kk)*Wi[kk][n+256j], f=2 except DC/Nyq.
// out flat = (b*2047+gi)*256 + n.
//
// Round 6: A-fragments load global->VGPR directly (no LDS round-trip for A;
// fragment = 16B/lane of contiguous bf16, 16 fully-used 64B lines per instr),
// prefetched 1 tile ahead into alternating named reg sets. LDS holds B only
// (depth-3, 48KB): per-iter LDS traffic 72KB -> 32KB. Linear prep_A transcode.

#define BATCH    8
#define NFRAMES  2048
#define FREQ     513
#define NFFT     1024
#define OUTCOLS  524032
#define NKT      68            // K'' = 4352 = 68*64
#define APITCH   2176          // bytes per A-image row (1088 bf16)
#define BSB      (NKT * 32768) // 2,228,224 B (68 tiles x 2 halves x 16KB)
#define GUARDB   (64 * APITCH)
#define AIMG_OFF ((size_t)BSB + GUARDB)
#define WS_NEED  (AIMG_OFF + (size_t)16384 * APITCH + GUARDB)

#define PA_BLOCKS 4352         // 4352*256 = 16384*68 (16-elem groups)
#define PB_BLOCKS 2176         // 2176*256 = 136*4096 dwords

typedef __attribute__((ext_vector_type(8))) short bf16x8;
typedef __attribute__((ext_vector_type(4))) float f32x4;

__device__ __forceinline__ unsigned short f2bf(float x) {
    unsigned u = __float_as_uint(x);
    return (unsigned short)((u + 0x7fffu + ((u >> 16) & 1u)) >> 16);
}

// ============ merged prep: linear A transcode + swizzled B build ============
__global__ __launch_bounds__(256) void prep_AB(const float* __restrict__ re,
                                               const float* __restrict__ im,
                                               const float* __restrict__ Wr,
                                               const float* __restrict__ Wi,
                                               char* __restrict__ ws) {
    const int bx = blockIdx.x;
    if (bx < PA_BLOCKS) {
        // ---- A: linear bf16 image, 16 elems (32B) per thread ----
        unsigned gid = (unsigned)bx * 256u + threadIdx.x;
        unsigned row = gid / 68u;
        int g16 = (int)(gid - row * 68u);
        const float* src = (g16 < 34) ? (re + (size_t)row * FREQ) : (im + (size_t)row * FREQ);
        const int cbase = (g16 < 34) ? g16 * 16 : (g16 - 34) * 16;
        bf16x8 v0, v1;
#pragma unroll
        for (int e = 0; e < 8; ++e) {
            int c = cbase + e;
            v0[e] = (short)((c < FREQ) ? f2bf(src[c]) : 0);
        }
#pragma unroll
        for (int e = 0; e < 8; ++e) {
            int c = cbase + 8 + e;
            v1[e] = (short)((c < FREQ) ? f2bf(src[c]) : 0);
        }
        char* dst = ws + AIMG_OFF + (size_t)row * APITCH + g16 * 32;
        *(bf16x8*)dst = v0;
        *(bf16x8*)(dst + 16) = v1;
    } else {
        // ---- B: 68 tiles x 2 halves x [128 nn][64 k], XOR-pre-swizzled ----
        int id = (bx - PA_BLOCKS) * 256 + threadIdx.x;
        int hid  = id >> 12;        // kt*2+nh (0..135)
        int rem  = id & 4095;
        int nn   = rem >> 5;        // 0..127
        int dstd = rem & 31;        // stored dword-in-row
        int dsrc = dstd ^ ((nn & 7) << 2);
        int kt = hid >> 1, nh = hid & 1;
        int kg = kt * 64 + dsrc * 2;
        int j  = kg / 1088;
        int c  = kg - j * 1088;
        int col = nh * 128 + nn + 256 * j;
        unsigned short h[2];
#pragma unroll
        for (int e = 0; e < 2; ++e) {
            int ce = c + e;
            float v = 0.0f;
            if (ce < 544) {
                if (ce < FREQ) {
                    float f = (ce == 0 || ce == FREQ - 1) ? 1.0f : 2.0f;
                    v = f * Wr[(size_t)ce * NFFT + col];
                }
            } else {
                int ci = ce - 544;
                if (ci < FREQ) {
                    float f = (ci == 0 || ci == FREQ - 1) ? 1.0f : 2.0f;
                    v = -f * Wi[(size_t)ci * NFFT + col];
                }
            }
            h[e] = f2bf(v);
        }
        unsigned d = (unsigned)h[0] | ((unsigned)h[1] << 16);
        *(unsigned*)(ws + (size_t)hid * 16384 + nn * 128 + dstd * 4) = d;
    }
}

// ============ main: BM=64 x BN=128, A direct-to-reg, B LDS depth-3 ============
__global__ __launch_bounds__(256, 2) void istft_mfma6(
    const char* __restrict__ ws_c, const float* __restrict__ ola,
    float* __restrict__ out) {
    __shared__ __attribute__((aligned(16))) unsigned short Bbuf[3][128][64]; // 48KB
    __shared__ float s_wsum[256], s_ola0[256], s_ola3[256];

    const int tid = threadIdx.x;
    const int l   = tid & 63;
    const int w   = tid >> 6;   // 0..3 = N quarter (wave tile 64x32)

    // XCD-bijective swizzle (512 = 8*64): nh pairs adjacent on same XCD
    const int bx  = blockIdx.x;
    const int sid = (bx & 7) * 64 + (bx >> 3);
    const int mt  = sid >> 1;   // 0..255
    const int nh  = sid & 1;

    const char* Aimg = ws_c + AIMG_OFF;
    const char* Bimg = ws_c;

    {
        float o0 = ola[tid], o1 = ola[tid + 256], o2 = ola[tid + 512], o3 = ola[tid + 768];
        s_wsum[tid] = o0 + o1 + o2 + o3;
        s_ola0[tid] = o0;
        s_ola3[tid] = o3;
    }

    const int b_  = (mt * 64) >> 11;        // batch (uniform per block)
    const int gi0 = (mt * 64) & 2047;
    const bool edge_lo = (gi0 == 0);
    const bool edge_hi = (gi0 == 1984);

    // per-lane A-frag base: row t = gi0 + 2 + (l&15) at j=0,mb=0; k-elem (l>>4)*8
    const char* abase = Aimg + (size_t)(b_ * 2048 + gi0 + 2 + (l & 15)) * APITCH
                      + ((l >> 4) << 4);

    f32x4 acc[4][2];
#pragma unroll
    for (int i = 0; i < 4; ++i)
#pragma unroll
        for (int n = 0; n < 2; ++n) acc[i][n] = (f32x4){0.f, 0.f, 0.f, 0.f};

    bf16x8 aE[4][2], aO[4][2];              // alternating A-frag sets
    const bf16x8 z8 = (bf16x8){0,0,0,0,0,0,0,0};

    int jn = 0, ktn = 0;                    // j/ktm of the NEXT tile to A-load

    auto LOAD_A = [&](bf16x8 (&aN)[4][2]) {
        const char* p = abase + (ptrdiff_t)ktn * 128 - (ptrdiff_t)jn * APITCH;
#pragma unroll
        for (int mb = 0; mb < 4; ++mb) {
            aN[mb][0] = *(const bf16x8*)(p + mb * 34816);
            aN[mb][1] = *(const bf16x8*)(p + mb * 34816 + 64);
        }
        if (edge_lo && jn == 3 && (l & 15) == 0) { aN[0][0] = z8; aN[0][1] = z8; }
        if (edge_hi) {
            if (jn == 0 && (l & 15) >= 14) { aN[3][0] = z8; aN[3][1] = z8; }
            if (jn == 1 && (l & 15) == 15) { aN[3][0] = z8; aN[3][1] = z8; }
        }
        if (++ktn == 17) { ktn = 0; ++jn; }
    };

    auto STAGE_B = [&](int kt, int buf) {
        const char* bsrc = Bimg + (size_t)(kt * 2 + nh) * 16384 + (size_t)tid * 16;
        char* bdst = (char*)&Bbuf[buf][0][0] + w * 1024;  // wave-uniform; HW adds lane*16
#pragma unroll
        for (int c = 0; c < 4; ++c)
            __builtin_amdgcn_global_load_lds(
                (const __attribute__((address_space(1))) unsigned*)(bsrc + c * 4096),
                (__attribute__((address_space(3))) unsigned*)(bdst + c * 4096), 16, 0, 0);
    };

    auto COMPUTE = [&](int buf, bf16x8 (&aC)[4][2]) {
        const char* Bb = (const char*)&Bbuf[buf][0][0];
#pragma unroll
        for (int ks = 0; ks < 2; ++ks) {
            const int grpK = ks * 4 + (l >> 4);
            bf16x8 bfr[2];
#pragma unroll
            for (int nb = 0; nb < 2; ++nb) {
                int nn = w * 32 + nb * 16 + (l & 15);
                bfr[nb] = *(const bf16x8*)(Bb + nn * 128 + ((grpK ^ (nn & 7)) << 4));
            }
            __builtin_amdgcn_s_setprio(1);
#pragma unroll
            for (int mb = 0; mb < 4; ++mb)
#pragma unroll
                for (int nb = 0; nb < 2; ++nb)
                    acc[mb][nb] = __builtin_amdgcn_mfma_f32_16x16x32_bf16(aC[mb][ks], bfr[nb], acc[mb][nb], 0, 0, 0);
            __builtin_amdgcn_s_setprio(0);
        }
    };

    // ---- prologue: B(0), A(0)->aE, B(1); need B0+A0 -> vmcnt(4) ----
    STAGE_B(0, 0);
    LOAD_A(aE);
    STAGE_B(1, 1);
    asm volatile("s_waitcnt vmcnt(4)" ::: "memory");
    __builtin_amdgcn_s_barrier();
    __builtin_amdgcn_sched_barrier(0);

    // ---- main loop: unroll-2 over named A-sets ----
#define BODY(I, ACUR, ANXT)                                                   \
    {                                                                         \
        const int rem = NKT - (I);                                            \
        if (rem > 2) STAGE_B((I) + 2, ((I) + 2) % 3);                         \
        if (rem > 1) LOAD_A(ANXT);                                            \
        if (rem > 2)      { asm volatile("s_waitcnt vmcnt(12)" ::: "memory"); } \
        else if (rem == 2){ asm volatile("s_waitcnt vmcnt(8)"  ::: "memory"); } \
        else              { asm volatile("s_waitcnt vmcnt(0)"  ::: "memory"); } \
        __builtin_amdgcn_s_barrier();                                         \
        __builtin_amdgcn_sched_barrier(0);                                    \
        COMPUTE((I) % 3, ACUR);                                               \
        __builtin_amdgcn_s_barrier();                                         \
        __builtin_amdgcn_sched_barrier(0);                                    \
    }

    for (int i = 0; i < NKT; i += 2) {
        BODY(i, aE, aO);
        BODY(i + 1, aO, aE);
    }
#undef BODY

    // ---- epilogue: /wsum with edge corrections, direct store ----
#pragma unroll
    for (int mb = 0; mb < 4; ++mb) {
#pragma unroll
        for (int rr = 0; rr < 4; ++rr) {
            int ml = mb * 16 + (l >> 4) * 4 + rr;
            int mg = mt * 64 + ml;
            int bb = mg >> 11;
            int gi = mg & 2047;
            if (gi > 2046) continue;
#pragma unroll
            for (int nb = 0; nb < 2; ++nb) {
                int n = nh * 128 + w * 32 + nb * 16 + (l & 15);
                float wsv = s_wsum[n];
                if (gi == 0)    wsv -= s_ola3[n];
                if (gi == 2046) wsv -= s_ola0[n];
                wsv = fmaxf(wsv, 1e-11f);
                out[(size_t)(bb * 2047 + gi) * 256 + n] = acc[mb][nb][rr] / wsv;
            }
        }
    }
}

// ---------------- last-resort naive fallback ----------------
__global__ __launch_bounds__(256) void istft_naive(
    const float* __restrict__ re, const float* __restrict__ im,
    const float* __restrict__ Wr, const float* __restrict__ Wi,
    const float* __restrict__ ola, float* __restrict__ out) {
    const int g = blockIdx.x + 2, b = blockIdx.y, ls = threadIdx.x;
    __shared__ float s_fr[4][FREQ];
    __shared__ float s_fi[4][FREQ];
#pragma unroll
    for (int jj = 0; jj < 4; ++jj) {
        const int t = g - jj;
        const bool valid = (t >= 0 && t < NFRAMES);
        const size_t base = ((size_t)b * NFRAMES + (valid ? t : 0)) * FREQ;
        for (int k = ls; k < FREQ; k += 256) {
            const float f = (k == 0 || k == FREQ - 1) ? 1.0f : 2.0f;
            s_fr[jj][k] = valid ? re[base + k] * f : 0.0f;
            s_fi[jj][k] = valid ? im[base + k] * f : 0.0f;
        }
    }
    __syncthreads();
    const float* wr = Wr + ls;
    const float* wi = Wi + ls;
    float acc = 0.0f;
    for (int k = 0; k < FREQ; ++k) {
        const float* wrk = wr + (size_t)k * NFFT;
        const float* wik = wi + (size_t)k * NFFT;
#pragma unroll
        for (int jj = 0; jj < 4; ++jj) {
            acc = fmaf(wrk[jj * 256], s_fr[jj][k], acc);
            acc = fmaf(-wik[jj * 256], s_fi[jj][k], acc);
        }
    }
    float wsv = 0.0f;
#pragma unroll
    for (int jj = 0; jj < 4; ++jj) {
        const int t = g - jj;
        if (t >= 0 && t < NFRAMES) wsv += ola[ls + jj * 256];
    }
    wsv = fmaxf(wsv, 1e-11f);
    out[(size_t)b * OUTCOLS + (g * 256 + ls - 512)] = acc / wsv;
}

extern "C" void kernel_launch(void* const* d_in, const int* in_sizes, int n_in,
                              void* d_out, int out_size, void* d_ws, size_t ws_size,
                              hipStream_t stream) {
    const float* re  = (const float*)d_in[0];
    const float* im  = (const float*)d_in[1];
    const float* Wr  = (const float*)d_in[2];
    const float* Wi  = (const float*)d_in[3];
    const float* ola = (const float*)d_in[4];
    float* out = (float*)d_out;

    if (ws_size >= WS_NEED) {
        char* ws = (char*)d_ws;
        hipLaunchKernelGGL(prep_AB, dim3(PA_BLOCKS + PB_BLOCKS), dim3(256), 0, stream,
                           re, im, Wr, Wi, ws);
        hipLaunchKernelGGL(istft_mfma6, dim3(512), dim3(256), 0, stream, ws, ola, out);
    } else {
        dim3 grid(2047, BATCH);
        hipLaunchKernelGGL(istft_naive, grid, dim3(256), 0, stream, re, im, Wr, Wi, ola, out);
    }
}